// Round 10
// baseline (175.646 us; speedup 1.0000x reference)
//
#include <hip/hip_runtime.h>

// LBP block — per-wave LINEAR write streams (R10).
// Theory: R2/R4/R5/R9 (very different compute structures) all converge at
// ~48us kernel = 137MB stores at ~2.9 TB/s, while harness fills sustain
// 6.8 TB/s with long linear per-wave streams. So make every wave's stores a
// single contiguous ascending stream.
// Compute blocks (1024): bid -> (n, o, half). Wave wv owns 16 consecutive
// output rows of channel 3+o and writes them as one linear 16KB stream.
// Rolling register pipeline: Y(h-1),Y(h),Y(h+1) carried; each iter prefetches
// x row h+3 (3 ch) one iteration ahead of its use. 1.0x y redundancy.
// Copy blocks (24, trailing): linear memcpy of x into out[:,0:3].
// No __syncthreads anywhere; exp(w)/conv_w are block-uniform scalar loads.
//
// Numerics (do not change): y = (x0*cw0 + x1*cw1) + x2*cw2 sequentially with
// FMA contraction OFF to match the numpy reference; (c - s > 0) == (c > s)
// exactly for finite floats; y recompute across waves/blocks is bit-identical
// (same expression, same inputs). Lane-0/63 shuffle-halo garbage feeds only
// border columns (zeroed); border rows zeroed wave-uniformly. No VGPR cap
// (R8: min-waves bounds starve the allocator); plain stores (R7: nt regressed).

typedef float vfloat4 __attribute__((ext_vector_type(4)));

__global__ __launch_bounds__(512) void lbp_all(
    const float* __restrict__ x,
    const float* __restrict__ conv_w,
    const float* __restrict__ w,
    float* __restrict__ out)
{
#pragma clang fp contract(off)
    const int bid = blockIdx.x;
    const int tid = threadIdx.x;

    if (bid >= 1024) {                    // ---- trailing x-copy blocks ----
        const int idx = bid - 1024;       // 24 blocks: (n, ch)
        const int n = idx / 3, ch = idx % 3;
        const float* src = x   + ((size_t)n * 3  + ch) * 65536;
        float*       dst = out + ((size_t)n * 67 + ch) * 65536;
        #pragma unroll 8
        for (int k = 0; k < 32; ++k) {
            const int t = (tid + k * 512) * 4;
            *(vfloat4*)(dst + t) = *(const vfloat4*)(src + t);
        }
        return;
    }

    const int lane = tid & 63;
    const int wv   = tid >> 6;            // 0..7
    const int col  = lane * 4;
    const int n    = bid >> 7;            // consecutive bids -> consecutive
    const int o    = (bid & 127) >> 1;    // output slabs (write locality)
    const int half = bid & 1;
    const int r0   = half * 128 + wv * 16;   // wave's 16 contiguous rows

    const float cw0 = conv_w[o * 3 + 0];
    const float cw1 = conv_w[o * 3 + 1];
    const float cw2 = conv_w[o * 3 + 2];
    float e[8];
    #pragma unroll
    for (int i = 0; i < 8; ++i) e[i] = expf(w[o * 8 + i]);

    const float* xn = x + (size_t)n * 3 * 65536;

#define LOADROW(ROW, DST)                                                    \
    {                                                                        \
        int _r = (ROW); _r = _r < 0 ? 0 : (_r > 255 ? 255 : _r);             \
        DST[0] = *(const vfloat4*)(xn + _r * 256 + col);                     \
        DST[1] = *(const vfloat4*)(xn + 65536  + _r * 256 + col);            \
        DST[2] = *(const vfloat4*)(xn + 131072 + _r * 256 + col);            \
    }

#define YROW(SRC, DST)                                                       \
    {                                                                        \
        float _yx = SRC[0].x * cw0 + SRC[1].x * cw1 + SRC[2].x * cw2;        \
        float _yy = SRC[0].y * cw0 + SRC[1].y * cw1 + SRC[2].y * cw2;        \
        float _yz = SRC[0].z * cw0 + SRC[1].z * cw1 + SRC[2].z * cw2;        \
        float _yw = SRC[0].w * cw0 + SRC[1].w * cw1 + SRC[2].w * cw2;        \
        DST[1] = _yx; DST[2] = _yy; DST[3] = _yz; DST[4] = _yw;              \
        DST[0] = __shfl_up(_yw, 1);   /* lane 0 garbage -> col 0 zeroed */   \
        DST[5] = __shfl_down(_yx, 1); /* lane 63 garbage -> col 255 zeroed */\
    }

    float Y0[6], Y1[6], Y2[6];            // y rows h-1, h, h+1 (cols -1..+4)
    vfloat4 xa[3], xb[3];                 // x-row prefetch double buffer
    {
        vfloat4 t[3];
        LOADROW(r0 - 1, t); YROW(t, Y0);
        LOADROW(r0,     t); YROW(t, Y1);
        LOADROW(r0 + 1, t); YROW(t, Y2);
        LOADROW(r0 + 2, xa);
    }

    float* op = out + ((((size_t)n * 67 + 3 + o) * 256 + r0) * 256 + col);

#define BODY(IT, CUR, NXT)                                                   \
    {                                                                        \
        const int _h = r0 + (IT);                                            \
        LOADROW(_h + 3, NXT);             /* prefetch, used next iter */     \
        float res[4];                                                        \
        if (_h == 0 || _h == 255) {       /* wave-uniform border rows */     \
            res[0] = res[1] = res[2] = res[3] = 0.f;                         \
        } else {                                                             \
            _Pragma("unroll")                                                \
            for (int j = 0; j < 4; ++j) {                                    \
                const float c = Y1[j + 1];                                   \
                float acc;                                                   \
                acc  = (c > Y0[j    ]) ? e[0] : 0.f;   /* (-1,-1) */         \
                acc += (c > Y0[j + 1]) ? e[1] : 0.f;   /* (-1, 0) */         \
                acc += (c > Y0[j + 2]) ? e[2] : 0.f;   /* (-1,+1) */         \
                acc += (c > Y1[j    ]) ? e[3] : 0.f;   /* ( 0,-1) */         \
                acc += (c > Y2[j    ]) ? e[4] : 0.f;   /* (+1,-1) */         \
                acc += (c > Y2[j + 1]) ? e[5] : 0.f;   /* (+1, 0) */         \
                acc += (c > Y2[j + 2]) ? e[6] : 0.f;   /* (+1,+1) */         \
                acc += (c > Y1[j + 2]) ? e[7] : 0.f;   /* ( 0,+1) */         \
                res[j] = acc;                                                \
            }                                                                \
            if (lane == 0)  res[0] = 0.f;  /* col 0 */                       \
            if (lane == 63) res[3] = 0.f;  /* col 255 */                     \
        }                                                                    \
        vfloat4 rv; rv.x = res[0]; rv.y = res[1]; rv.z = res[2]; rv.w = res[3]; \
        *(vfloat4*)(op + (size_t)(IT) * 256) = rv;   /* linear stream */     \
        _Pragma("unroll")                                                    \
        for (int q = 0; q < 6; ++q) { Y0[q] = Y1[q]; Y1[q] = Y2[q]; }        \
        YROW(CUR, Y2);                    /* y row h+2 from prefetched x */  \
    }

    for (int it = 0; it < 16; it += 2) {  // 8 trips, A/B buffer rename
        BODY(it,     xa, xb);
        BODY(it + 1, xb, xa);
    }
#undef BODY
#undef YROW
#undef LOADROW
}

extern "C" void kernel_launch(void* const* d_in, const int* in_sizes, int n_in,
                              void* d_out, int out_size, void* d_ws, size_t ws_size,
                              hipStream_t stream) {
    const float* x      = (const float*)d_in[0];
    const float* conv_w = (const float*)d_in[1];
    const float* w      = (const float*)d_in[2];
    float* out          = (float*)d_out;

    dim3 grid(1048);    // 1024 compute blocks (n,o,half) + 24 copy blocks
    dim3 block(512);
    hipLaunchKernelGGL(lbp_all, grid, block, 0, stream, x, conv_w, w, out);
}